// Round 4
// baseline (450.675 us; speedup 1.0000x reference)
//
#include <hip/hip_runtime.h>
#include <hip/hip_bf16.h>

#define S_SP 16384
#define NKV 512

typedef short short8 __attribute__((ext_vector_type(8)));
typedef short short4_t __attribute__((ext_vector_type(4)));
typedef float v4f   __attribute__((ext_vector_type(4)));

__device__ __forceinline__ unsigned short f2bf(float x){
  union { float f; unsigned u; } v; v.f = x;
  unsigned r = v.u + 0x7FFFu + ((v.u >> 16) & 1u);
  return (unsigned short)(r >> 16);
}
__device__ __forceinline__ float bf2f(unsigned short h){
  union { unsigned u; float f; } v; v.u = ((unsigned)h) << 16; return v.f;
}

#if defined(__has_builtin)
#if __has_builtin(__builtin_amdgcn_cvt_pk_bf16_f32)
#define HAVE_PKBF 1
#endif
#endif

__device__ __forceinline__ unsigned pk2(float a, float b){
#ifdef HAVE_PKBF
  typedef __bf16 bf16x2 __attribute__((ext_vector_type(2)));
  union { bf16x2 v; unsigned u; } r;
  r.v = __builtin_amdgcn_cvt_pk_bf16_f32(a, b);
  return r.u;
#else
  return (unsigned)f2bf(a) | ((unsigned)f2bf(b) << 16);
#endif
}

__device__ __forceinline__ v4f mfma16(short4_t a, short4_t b, v4f c){
#if __has_builtin(__builtin_amdgcn_mfma_f32_16x16x16bf16_1k)
  return __builtin_amdgcn_mfma_f32_16x16x16bf16_1k(a, b, c, 0, 0, 0);
#else
  asm volatile("s_nop 1\n\tv_mfma_f32_16x16x16_bf16 %0, %1, %2, %0"
               : "+v"(c) : "v"(a), "v"(b));
  return c;
#endif
}

__device__ __forceinline__ void dma16(const void* g, void* l){
  __builtin_amdgcn_global_load_lds((const __attribute__((address_space(1))) unsigned int*)g,
                                   (__attribute__((address_space(3))) unsigned int*)l, 16, 0, 0);
}
__device__ __forceinline__ void bar_lgkm(){ asm volatile("s_waitcnt lgkmcnt(0)\n\ts_barrier" ::: "memory"); }
__device__ __forceinline__ void bar_vm2(){ asm volatile("s_waitcnt vmcnt(2)\n\ts_barrier" ::: "memory"); }
__device__ __forceinline__ void bar_vm0(){ asm volatile("s_waitcnt vmcnt(0)\n\ts_barrier" ::: "memory"); }

// ---------------- K0: one-time w_out fp32 -> bf16 --------------------------
__global__ __launch_bounds__(256) void k_wcvt(const float* __restrict__ w,
                                              unsigned short* __restrict__ o){
  int i = (blockIdx.x*256 + threadIdx.x)*8;
  v4f a = *(const v4f*)(w+i), b = *(const v4f*)(w+i+4);
  uint4 u;
  u.x = pk2(a[0],a[1]); u.y = pk2(a[2],a[3]);
  u.z = pk2(b[0],b[1]); u.w = pk2(b[2],b[3]);
  *(uint4*)(o+i) = u;
}

// ---------------- K1: channel-LN stats (mean, 1/(std+eps)) for ctx & qs ----
__global__ __launch_bounds__(256) void k_stats(const float* __restrict__ ctx,
                                               const float* __restrict__ qs,
                                               float* __restrict__ MEAN,
                                               float* __restrict__ INV){
  __shared__ float r1[4][64];
  __shared__ float r2[4][64];
  int bx = blockIdx.x;
  int tt = bx >> 9; int b = (bx >> 8) & 1; int sc = bx & 255;
  int t = threadIdx.x;
  int sv = t & 63, cg = t >> 6;
  int s = sc*64 + sv;
  const float* src = (tt ? qs : ctx) + ((size_t)b*128 + cg*32)*S_SP + s;
  float sum = 0.f, ss = 0.f;
  #pragma unroll 8
  for (int c = 0; c < 32; c++){
    float v = src[(size_t)c*S_SP];
    sum += v; ss += v*v;
  }
  r1[cg][sv] = sum; r2[cg][sv] = ss;
  __syncthreads();
  if (t < 64){
    float sm = r1[0][t]+r1[1][t]+r1[2][t]+r1[3][t];
    float sq = r2[0][t]+r2[1][t]+r2[2][t]+r2[3][t];
    float mean = sm * 0.0078125f;
    float var  = fmaxf(sq * 0.0078125f - mean*mean, 0.f);
    int o = tt*2*S_SP + b*S_SP + sc*64 + t;
    MEAN[o] = mean;
    INV[o]  = 1.f/(sqrtf(var) + 1e-6f);
  }
}

// ---------------- K2: fused LN + projection, W-broadcast register GEMM -----
template<int ISK>
__global__ __launch_bounds__(256) void k_projT(
    const float* __restrict__ src, const float* __restrict__ wmat,
    const float* __restrict__ gam, const float* __restrict__ bet,
    const float* __restrict__ MEAN, const float* __restrict__ INV,
    unsigned short* __restrict__ QBF, float* __restrict__ QP,
    float* __restrict__ SCORE){
  __shared__ __align__(16) float xlds[32*256];
  __shared__ __align__(16) float wlds[32*128];
  __shared__ float nbuf[4][256];
  __shared__ float ibuf[2][256];
  __shared__ float qpl[128];
  __shared__ float SCP[4][44];
  int bx = blockIdx.x;
  int og = bx & 3, stile = (bx>>2)&63, b = bx>>8;
  int s0 = stile*256;
  int t = threadIdx.x;
  int w = t>>6, lane = t&63;
  int ow0 = w*32;
  int tt = ISK ? 0 : 1;
  const float* Mn = MEAN + tt*32768 + b*16384 + s0;
  const float* Iv = INV  + tt*32768 + b*16384 + s0;
  const float* WB = wmat + (size_t)og*128*128;
  if (ISK){ if (t < 128) qpl[t] = QP[(b*8 + og*2)*64 + t]; }
  int col = lane*4;
  v4f mv = *(const v4f*)(Mn + col);
  v4f vv = *(const v4f*)(Iv + col);
  v4f acc[32];
  #pragma unroll
  for (int i=0;i<32;i++) acc[i] = (v4f){0.f,0.f,0.f,0.f};
  for (int kc=0;kc<4;kc++){
    __syncthreads();
    #pragma unroll
    for (int i=0;i<8;i++){
      int kk = i*4 + w;
      int cgl = kc*32 + kk;
      v4f xv = *(const v4f*)(src + ((size_t)(b*128+cgl))*S_SP + s0 + col);
      float gg = gam[cgl], bb = bet[cgl];
      v4f r;
      #pragma unroll
      for (int j=0;j<4;j++) r[j] = gg*(xv[j]-mv[j])*vv[j] + bb;
      *(v4f*)&xlds[kk*256 + col] = r;
    }
    {
      int oc = t>>1, ks0 = (t&1)*16;
      const float* wr = WB + (size_t)oc*128 + kc*32 + ks0;
      v4f w0 = *(const v4f*)wr, w1 = *(const v4f*)(wr+4);
      v4f w2 = *(const v4f*)(wr+8), w3 = *(const v4f*)(wr+12);
      #pragma unroll
      for (int i=0;i<4;i++){
        wlds[(ks0+i   )*128+oc]=w0[i];
        wlds[(ks0+i+4 )*128+oc]=w1[i];
        wlds[(ks0+i+8 )*128+oc]=w2[i];
        wlds[(ks0+i+12)*128+oc]=w3[i];
      }
    }
    __syncthreads();
    #pragma unroll 2
    for (int kk=0;kk<32;kk++){
      v4f xv = *(const v4f*)&xlds[kk*256 + col];
      #pragma unroll
      for (int o8=0;o8<8;o8++){
        v4f w4 = *(const v4f*)&wlds[kk*128 + ow0 + o8*4];
        acc[o8*4+0] += xv*w4[0];
        acc[o8*4+1] += xv*w4[1];
        acc[o8*4+2] += xv*w4[2];
        acc[o8*4+3] += xv*w4[3];
      }
    }
  }
  v4f ss = {0.f,0.f,0.f,0.f};
  #pragma unroll
  for (int o=0;o<32;o++) ss += acc[o]*acc[o];
  *(v4f*)&nbuf[w][col] = ss;
  __syncthreads();
  if (t < 256){
    float a0 = nbuf[0][t]+nbuf[1][t];
    float a1 = nbuf[2][t]+nbuf[3][t];
    ibuf[0][t] = 1.f/fmaxf(sqrtf(a0),1e-12f);
    ibuf[1][t] = 1.f/fmaxf(sqrtf(a1),1e-12f);
  }
  __syncthreads();
  int hl = w>>1;
  v4f iv4 = *(const v4f*)&ibuf[hl][col];
  int head = og*2 + hl, bh = b*8 + head;
  if (!ISK){
    #pragma unroll
    for (int o=0;o<32;o++) acc[o] *= iv4;
    #pragma unroll
    for (int j=0;j<4;j++){
      int s = s0 + col + j;
      unsigned short* dst = QBF + ((size_t)bh*S_SP + s)*64 + (w&1)*32;
      #pragma unroll
      for (int v=0;v<4;v++){
        uint4 pk;
        pk.x = pk2(acc[v*8+0][j], acc[v*8+1][j]);
        pk.y = pk2(acc[v*8+2][j], acc[v*8+3][j]);
        pk.z = pk2(acc[v*8+4][j], acc[v*8+5][j]);
        pk.w = pk2(acc[v*8+6][j], acc[v*8+7][j]);
        *(uint4*)(dst + v*8) = pk;
      }
    }
    float mine = 0.f;
    #pragma unroll
    for (int o=0;o<32;o++){
      float v = acc[o][0]+acc[o][1]+acc[o][2]+acc[o][3];
      v += __shfl_xor(v,1,64); v += __shfl_xor(v,2,64); v += __shfl_xor(v,4,64);
      v += __shfl_xor(v,8,64); v += __shfl_xor(v,16,64); v += __shfl_xor(v,32,64);
      if (lane == o) mine = v;
    }
    if (lane < 32) atomicAdd(QP + bh*64 + (w&1)*32 + lane, mine);
  } else {
    v4f tj = {0.f,0.f,0.f,0.f};
    #pragma unroll
    for (int o=0;o<32;o++){
      float qw = qpl[ow0+o];
      v4f av;
      #pragma unroll
      for (int j=0;j<4;j++) av[j] = fabsf(acc[o][j]);
      tj += av*qw;
    }
    tj *= iv4;
    v4f twv = tj;
    #pragma unroll
    for (int m=8;m<=32;m<<=1){
      v4f o2;
      #pragma unroll
      for (int j=0;j<4;j++) o2[j] = __shfl_xor(twv[j], m, 64);
      twv += o2;
    }
    float th = tj[0]+tj[1]+tj[2]+tj[3];
    th += __shfl_xor(th,1,64); th += __shfl_xor(th,2,64); th += __shfl_xor(th,4,64);
    float td = twv[0]+twv[1]+twv[2]+twv[3];
    td += __shfl_xor(td,1,64); td += __shfl_xor(td,2,64); td += __shfl_xor(td,4,64);
    if (lane == 0) SCP[w][0] = td;
    if ((lane&7) == 0) SCP[w][1 + (lane>>3)] = th;
    if (lane < 8){
      #pragma unroll
      for (int j=0;j<4;j++) SCP[w][9 + lane*4 + j] = twv[j];
    }
    __syncthreads();
    if (t < 82){
      int hl2 = t/41, slot = t - hl2*41;
      float v = SCP[hl2*2][slot] + SCP[hl2*2+1][slot];
      int bh2 = b*8 + og*2 + hl2;
      int off;
      if (slot == 0) off = stile>>2;
      else if (slot < 9) off = 16 + (stile&3)*8 + (slot-1);
      else off = 48 + (slot-9);
      atomicAdd(SCORE + bh2*80 + off, v);
    }
  }
}

// ---------------- K3: top-8 per axis from accumulated scores ---------------
__global__ __launch_bounds__(64) void k_topk(const float* __restrict__ SCORE,
                                             int* __restrict__ IDX){
  int bh = blockIdx.x;
  if (threadIdx.x != 0) return;
  float sc[80];
  for (int i=0;i<80;i++) sc[i] = SCORE[bh*80+i];
  for (int a=0;a<3;a++){
    int n = a ? 32 : 16;
    int off = (a==0) ? 0 : (a==1 ? 16 : 48);
    for (int it=0; it<8; it++){
      int bi = 0; float bv = -3.4e38f;
      for (int i=0;i<n;i++){ float v = sc[off+i]; if (v > bv){ bv=v; bi=i; } }
      IDX[bh*24 + a*8 + it] = bi;
      sc[off+bi] = -3.4e38f;
    }
  }
}

// ---------------- K4: recompute gathered k (l2norm, bf16) and v (bf16^T) ---
__global__ __launch_bounds__(256) void k_gather(const float* __restrict__ ctx,
    const float* __restrict__ wkv, const float* __restrict__ ctx_g,
    const float* __restrict__ ctx_b, const float* __restrict__ MEAN,
    const float* __restrict__ INV, const int* __restrict__ IDX,
    unsigned short* __restrict__ KG, unsigned short* __restrict__ VGT){
  __shared__ float wlds[64*129];
  __shared__ float xln[32*128];
  __shared__ int sidx[24];
  int bx = blockIdx.x;
  int bh = bx >> 5, jc = (bx >> 1) & 15, type = bx & 1;
  int head = bh & 7, b = bh >> 3;
  int t = threadIdx.x;
  if (t < 24) sidx[t] = IDX[bh*24 + t];
  {
    int oc = t>>2, ks = (t&3)*32;
    const float* wr = wkv + ((size_t)(type*512 + head*64 + oc))*128 + ks;
    #pragma unroll 8
    for (int i=0;i<32;i++) wlds[oc*129 + ks + i] = wr[i];
  }
  __syncthreads();
  {
    int jl = t>>3, seg = (t&7)*16;
    int jj = jc*32 + jl;
    int dsel = sidx[jj>>6], hsel = sidx[8 + ((jj>>3)&7)], wsel = sidx[16 + (jj&7)];
    int sj = dsel*1024 + hsel*32 + wsel;
    float mn = MEAN[b*S_SP + sj];
    float iv = INV[b*S_SP + sj];
    #pragma unroll
    for (int i=0;i<16;i++){
      int cc = seg + i;
      float raw = ctx[((size_t)(b*128 + cc))*S_SP + sj];
      xln[jl*128 + cc] = ctx_g[cc]*(raw - mn)*iv + ctx_b[cc];
    }
  }
  __syncthreads();
  int c = t & 63, jg = t >> 6;
  float accv[8] = {};
  #pragma unroll 4
  for (int k=0;k<128;k++){
    float wv = wlds[c*129 + k];
    #pragma unroll
    for (int m=0;m<8;m++) accv[m] += wv * xln[(jg + 4*m)*128 + k];
  }
  #pragma unroll
  for (int m=0;m<8;m++){
    int jj = jc*32 + jg + 4*m;
    float a = accv[m];
    if (type == 0){
      float sq = a*a;
      #pragma unroll
      for (int mm=32; mm; mm>>=1) sq += __shfl_xor(sq, mm, 64);
      float rn = 1.f/fmaxf(sqrtf(sq), 1e-12f);
      KG[((size_t)bh*NKV + jj)*64 + c] = f2bf(a*rn);
    } else {
      VGT[((size_t)bh*64 + c)*NKV + jj] = f2bf(a);
    }
  }
}

// ---------------- K5: attention. DMA-staged KV, P stays in registers -------
// S^T = K.Q^T (16x16x32). C-layout (q=l15, j=quad*4+r) IS the A-layout of
// v_mfma_f32_16x16x16_bf16 (m=lane&15, k=quad*4+i) => O = P.V with zero
// P LDS traffic. Fixed-max softmax (|sim|<=1). KV staged via global_load_lds
// with conflict-free offset layouts; fine vmcnt barriers keep prefetch alive.
__global__ __launch_bounds__(512, 4) void k_attn(const unsigned short* __restrict__ QBF,
    const unsigned short* __restrict__ KG, const unsigned short* __restrict__ VGT,
    unsigned short* __restrict__ AOUT){
  __shared__ __align__(16) unsigned short kst0[8224]; // K chunk buf A (128j x 64c, group-offset)
  __shared__ __align__(16) unsigned short kst1[8224]; // K chunk buf B
  __shared__ __align__(16) unsigned short vst[8432];  // V chunk (64c x 128j, 528-stride groups)
  int bx = blockIdx.x;
  int bh = bx >> 5, qb = bx & 31;
  int t = threadIdx.x;
  int wv = t >> 6, lane = t & 63;
  int quad = lane >> 4, l15 = lane & 15;
  int q0 = qb*512 + wv*64;
  const unsigned short* kgb = KG + (size_t)bh*NKV*64;
  const unsigned short* vgb = VGT + (size_t)bh*64*NKV;
  const unsigned short* ksrcA = kgb + ((size_t)(wv*8 + (lane>>3))*64 + (lane&7)*8);
  const unsigned short* vsrcA = vgb + ((size_t)(wv*4 + (lane>>4))*512 + (lane&15)*8);
  int kdoffA = wv*512 + (wv&1)*32;
  unsigned short* vdstA = vst + wv*528;
  int koff = (l15>>3)*544 + (l15&7)*64 + quad*8;
  int voff = (l15>>2)*528 + (l15&3)*128 + quad*4;
  // Q fragments (B-operand): n=q=l15, k=c=quad*8+i
  short8 bq[4][2];
  #pragma unroll
  for (int qt=0; qt<4; qt++){
    const unsigned short* qp_ = QBF + ((size_t)bh*S_SP + q0 + qt*16 + l15)*64 + quad*8;
    union { uint4 u; short8 s; } u0, u1;
    u0.u = *(const uint4*)(qp_);
    u1.u = *(const uint4*)(qp_ + 32);
    bq[qt][0] = u0.s; bq[qt][1] = u1.s;
  }
  v4f oacc[4][4]; // [qt][ct]; O tile: col=c=l15, row=q=quad*4+r
  #pragma unroll
  for (int i=0;i<4;i++)
    #pragma unroll
    for (int j=0;j<4;j++) oacc[i][j] = (v4f){0.f,0.f,0.f,0.f};
  float lsum[4] = {0.f,0.f,0.f,0.f};
  // prologue: K chunk 0 (2 DMA instrs per wave)
  dma16(ksrcA, kst0 + kdoffA);
  dma16(ksrcA + 4096, kst0 + kdoffA + 4096);
  for (int ch=0; ch<4; ch++){
    unsigned short* kb = (ch&1) ? kst1 : kst0;
    bar_lgkm();                       // V buf free across waves; K prefetch stays in flight
    dma16(vsrcA + ch*128, vdstA);
    dma16(vsrcA + ch*128 + 16384, vdstA + 4224);
    if (ch < 3){
      unsigned short* kn = (ch&1) ? kst0 : kst1;
      dma16(ksrcA + (ch+1)*8192, kn + kdoffA);
      dma16(ksrcA + (ch+1)*8192 + 4096, kn + kdoffA + 4096);
      bar_vm2();                      // drain K(ch)+V(ch), keep K(ch+1) in flight
    } else {
      bar_vm0();
    }
    #pragma unroll 2
    for (int jt=0; jt<8; jt++){
      const unsigned short* kr = kb + jt*1024 + koff;
      union { uint4 u; short8 s; } a0, a1;
      a0.u = *(const uint4*)(kr);
      a1.u = *(const uint4*)(kr + 32);
      short4_t bV[4];
      #pragma unroll
      for (int ct=0; ct<4; ct++){
        union { uint2 u2; short4_t s; } vvv;
        vvv.u2 = *(const uint2*)(vst + ct*2112 + voff + jt*16);
        bV[ct] = vvv.s;
      }
      #pragma unroll
      for (int qt=0; qt<4; qt++){
        v4f z = {0.f,0.f,0.f,0.f};
        z = __builtin_amdgcn_mfma_f32_16x16x32_bf16(a0.s, bq[qt][0], z, 0, 0, 0);
        z = __builtin_amdgcn_mfma_f32_16x16x32_bf16(a1.s, bq[qt][1], z, 0, 0, 0);
        v4f p;
        #pragma unroll
        for (int r=0;r<4;r++) p[r] = __expf(z[r] - 1.0f);
        lsum[qt] += (p[0]+p[1]) + (p[2]+p[3]);
        union { unsigned u[2]; short4_t s; } pa;
        pa.u[0] = pk2(p[0], p[1]);
        pa.u[1] = pk2(p[2], p[3]);
        #pragma unroll
        for (int ct=0; ct<4; ct++)
          oacc[qt][ct] = mfma16(pa.s, bV[ct], oacc[qt][ct]);
      }
    }
  }
  #pragma unroll
  for (int qt=0; qt<4; qt++){
    float l = lsum[qt];
    l += __shfl_xor(l, 16, 64);
    l += __shfl_xor(l, 32, 64);
    float rl = 1.f / l;
    #pragma unroll
    for (int r=0; r<4; r++){
      float rr = __shfl(rl, quad*4 + r, 64);
      size_t base = ((size_t)bh*S_SP + q0 + qt*16 + quad*4 + r)*64 + l15;
      #pragma unroll
      for (int ct=0; ct<4; ct++)
        AOUT[base + ct*16] = f2bf(oacc[qt][ct][r]*rr);
    }
  }
}

// ---------------- K6: out-projection, W/A straight from L2 + LN + residual --
__global__ __launch_bounds__(256) void k_out(const unsigned short* __restrict__ AOUT,
    const unsigned short* __restrict__ WBF, const float* __restrict__ out_g,
    const float* __restrict__ out_b, const float* __restrict__ gamma,
    const float* __restrict__ qsrc, float* __restrict__ OUT){
  __shared__ float lnp[4][2][64];
  __shared__ float mbuf[64], sbuf[64], ogl[128], obl[128];
  int bx = blockIdx.x; int b = bx>>8; int stile = bx&255; int s0 = stile*64;
  int t = threadIdx.x; int w = t>>6; int lane = t&63;
  int q = lane>>4; int l15 = lane&15;
  if (t < 128){ ogl[t] = out_g[t]; obl[t] = out_b[t]; }
  v4f acc[2][4];
  #pragma unroll
  for (int i=0;i<2;i++)
    #pragma unroll
    for (int j=0;j<4;j++) acc[i][j] = (v4f){0.f,0.f,0.f,0.f};
  #pragma unroll 4
  for (int kt=0; kt<16; kt++){
    union { uint4 u; short8 s; } af0, af1;
    const unsigned short* wr = WBF + (size_t)(w*32 + l15)*512 + kt*32 + q*8;
    af0.u = *(const uint4*)(wr);
    af1.u = *(const uint4*)(wr + 16*512);
    int head = kt>>1; int cc0 = (kt&1)*32 + q*8;
    const unsigned short* bp = AOUT + ((size_t)((b*8+head)*S_SP + s0 + l15))*64 + cc0;
    #pragma unroll
    for (int nt=0;nt<4;nt++){
      union { uint4 u; short8 s; } ub;
      ub.u = *(const uint4*)(bp + (size_t)nt*16*64);
      acc[0][nt] = __builtin_amdgcn_mfma_f32_16x16x32_bf16(af0.s, ub.s, acc[0][nt], 0, 0, 0);
      acc[1][nt] = __builtin_amdgcn_mfma_f32_16x16x32_bf16(af1.s, ub.s, acc[1][nt], 0, 0, 0);
    }
  }
  #pragma unroll
  for (int nt=0;nt<4;nt++){
    float p1 = 0.f, p2 = 0.f;
    #pragma unroll
    for (int mt=0;mt<2;mt++)
      #pragma unroll
      for (int r=0;r<4;r++){ float v = acc[mt][nt][r]; p1 += v; p2 += v*v; }
    p1 += __shfl_xor(p1,16,64); p1 += __shfl_xor(p1,32,64);
    p2 += __shfl_xor(p2,16,64); p2 += __shfl_xor(p2,32,64);
    if (q == 0){ lnp[w][0][nt*16+l15] = p1; lnp[w][1][nt*16+l15] = p2; }
  }
  __syncthreads();
  if (t < 64){
    float m = (lnp[0][0][t]+lnp[1][0][t]+lnp[2][0][t]+lnp[3][0][t]) * 0.0078125f;
    float qq = (lnp[0][1][t]+lnp[1][1][t]+lnp[2][1][t]+lnp[3][1][t]) * 0.0078125f;
    float var = fmaxf(qq - m*m, 0.f);
    mbuf[t] = m;
    sbuf[t] = 1.f/(sqrtf(var) + 1e-6f);
  }
  __syncthreads();
  float gs = gamma[0];
  #pragma unroll
  for (int nt=0;nt<4;nt++){
    int sl = nt*16 + l15;
    float mm = mbuf[sl], ssc = sbuf[sl];
    #pragma unroll
    for (int mt=0;mt<2;mt++){
      #pragma unroll
      for (int r=0;r<4;r++){
        int c = w*32 + mt*16 + q*4 + r;
        size_t adr = ((size_t)(b*128+c))*S_SP + s0 + sl;
        float yn = (acc[mt][nt][r]-mm)*ssc;
        OUT[adr] = gs*(ogl[c]*yn + obl[c]) + qsrc[adr];
      }
    }
  }
}

extern "C" void kernel_launch(void* const* d_in, const int* in_sizes, int n_in,
                              void* d_out, int out_size, void* d_ws, size_t ws_size,
                              hipStream_t stream){
  const float* qsrc  = (const float*)d_in[0];
  const float* ctx   = (const float*)d_in[1];
  const float* wq    = (const float*)d_in[2];
  const float* wkv   = (const float*)d_in[3];
  const float* wout  = (const float*)d_in[4];
  const float* ctx_g = (const float*)d_in[5];
  const float* ctx_b = (const float*)d_in[6];
  const float* qs_g  = (const float*)d_in[7];
  const float* qs_b  = (const float*)d_in[8];
  const float* out_g = (const float*)d_in[9];
  const float* out_b = (const float*)d_in[10];
  const float* gamma = (const float*)d_in[11];
  float* OUT = (float*)d_out;
  char* ws = (char*)d_ws;
  float* QP    = (float*)(ws);
  float* SCORE = (float*)(ws + 4096);
  float* MEAN  = (float*)(ws + 16384);
  float* INV   = (float*)(ws + 278528);
  int*   IDX   = (int*)(ws + 540672);
  unsigned short* QBF  = (unsigned short*)(ws + 544768);
  unsigned short* KG   = (unsigned short*)(ws + 34099200);
  unsigned short* VGT  = (unsigned short*)(ws + 35147776);
  unsigned short* AOUT = (unsigned short*)(ws + 36196352);
  unsigned short* WBF  = (unsigned short*)(ws + 69750784);

  hipMemsetAsync(ws, 0, 9216, stream); // QP + SCORE
  k_wcvt<<<32, 256, 0, stream>>>(wout, WBF);
  k_stats<<<1024, 256, 0, stream>>>(ctx, qsrc, MEAN, INV);
  k_projT<0><<<512, 256, 0, stream>>>(qsrc, wq, qs_g, qs_b, MEAN, INV, QBF, QP, SCORE);
  k_projT<1><<<512, 256, 0, stream>>>(ctx, wkv, ctx_g, ctx_b, MEAN, INV, QBF, QP, SCORE);
  k_topk<<<16, 64, 0, stream>>>(SCORE, IDX);
  k_gather<<<512, 256, 0, stream>>>(ctx, wkv, ctx_g, ctx_b, MEAN, INV, IDX, KG, VGT);
  k_attn<<<512, 512, 0, stream>>>(QBF, KG, VGT, AOUT);
  k_out<<<512, 256, 0, stream>>>(AOUT, WBF, out_g, out_b, gamma, qsrc, OUT);
}

// Round 5
// 424.569 us; speedup vs baseline: 1.0615x; 1.0615x over previous
//
#include <hip/hip_runtime.h>
#include <hip/hip_bf16.h>

#define S_SP 16384
#define NKV 512

typedef short short8 __attribute__((ext_vector_type(8)));
typedef short short4_t __attribute__((ext_vector_type(4)));
typedef float v4f   __attribute__((ext_vector_type(4)));

__device__ __forceinline__ unsigned short f2bf(float x){
  union { float f; unsigned u; } v; v.f = x;
  unsigned r = v.u + 0x7FFFu + ((v.u >> 16) & 1u);
  return (unsigned short)(r >> 16);
}
__device__ __forceinline__ float bf2f(unsigned short h){
  union { unsigned u; float f; } v; v.u = ((unsigned)h) << 16; return v.f;
}

#if defined(__has_builtin)
#if __has_builtin(__builtin_amdgcn_cvt_pk_bf16_f32)
#define HAVE_PKBF 1
#endif
#endif

__device__ __forceinline__ unsigned pk2(float a, float b){
#ifdef HAVE_PKBF
  typedef __bf16 bf16x2 __attribute__((ext_vector_type(2)));
  union { bf16x2 v; unsigned u; } r;
  r.v = __builtin_amdgcn_cvt_pk_bf16_f32(a, b);
  return r.u;
#else
  return (unsigned)f2bf(a) | ((unsigned)f2bf(b) << 16);
#endif
}

__device__ __forceinline__ v4f mfma16(short4_t a, short4_t b, v4f c){
#if __has_builtin(__builtin_amdgcn_mfma_f32_16x16x16bf16_1k)
  return __builtin_amdgcn_mfma_f32_16x16x16bf16_1k(a, b, c, 0, 0, 0);
#else
  asm volatile("s_nop 1\n\tv_mfma_f32_16x16x16_bf16 %0, %1, %2, %0"
               : "+v"(c) : "v"(a), "v"(b));
  return c;
#endif
}

__device__ __forceinline__ void dma16(const void* g, void* l){
  __builtin_amdgcn_global_load_lds((const __attribute__((address_space(1))) unsigned int*)g,
                                   (__attribute__((address_space(3))) unsigned int*)l, 16, 0, 0);
}
__device__ __forceinline__ void bar_lgkm(){ asm volatile("s_waitcnt lgkmcnt(0)\n\ts_barrier" ::: "memory"); }
__device__ __forceinline__ void bar_vm2(){ asm volatile("s_waitcnt vmcnt(2)\n\ts_barrier" ::: "memory"); }
__device__ __forceinline__ void bar_vm0(){ asm volatile("s_waitcnt vmcnt(0)\n\ts_barrier" ::: "memory"); }

// ---------------- K0: one-time w_out fp32 -> bf16 --------------------------
__global__ __launch_bounds__(256) void k_wcvt(const float* __restrict__ w,
                                              unsigned short* __restrict__ o){
  int i = (blockIdx.x*256 + threadIdx.x)*8;
  v4f a = *(const v4f*)(w+i), b = *(const v4f*)(w+i+4);
  uint4 u;
  u.x = pk2(a[0],a[1]); u.y = pk2(a[2],a[3]);
  u.z = pk2(b[0],b[1]); u.w = pk2(b[2],b[3]);
  *(uint4*)(o+i) = u;
}

// ---------------- K1: channel-LN stats (mean, 1/(std+eps)) for ctx & qs ----
__global__ __launch_bounds__(256) void k_stats(const float* __restrict__ ctx,
                                               const float* __restrict__ qs,
                                               float* __restrict__ MEAN,
                                               float* __restrict__ INV){
  __shared__ float r1[4][64];
  __shared__ float r2[4][64];
  int bx = blockIdx.x;
  int tt = bx >> 9; int b = (bx >> 8) & 1; int sc = bx & 255;
  int t = threadIdx.x;
  int sv = t & 63, cg = t >> 6;
  int s = sc*64 + sv;
  const float* src = (tt ? qs : ctx) + ((size_t)b*128 + cg*32)*S_SP + s;
  float sum = 0.f, ss = 0.f;
  #pragma unroll 8
  for (int c = 0; c < 32; c++){
    float v = src[(size_t)c*S_SP];
    sum += v; ss += v*v;
  }
  r1[cg][sv] = sum; r2[cg][sv] = ss;
  __syncthreads();
  if (t < 64){
    float sm = r1[0][t]+r1[1][t]+r1[2][t]+r1[3][t];
    float sq = r2[0][t]+r2[1][t]+r2[2][t]+r2[3][t];
    float mean = sm * 0.0078125f;
    float var  = fmaxf(sq * 0.0078125f - mean*mean, 0.f);
    int o = tt*2*S_SP + b*S_SP + sc*64 + t;
    MEAN[o] = mean;
    INV[o]  = 1.f/(sqrtf(var) + 1e-6f);
  }
}

// ---------------- K2: fused LN + projection, W-broadcast register GEMM -----
template<int ISK>
__global__ __launch_bounds__(256) void k_projT(
    const float* __restrict__ src, const float* __restrict__ wmat,
    const float* __restrict__ gam, const float* __restrict__ bet,
    const float* __restrict__ MEAN, const float* __restrict__ INV,
    unsigned short* __restrict__ QBF, float* __restrict__ QP,
    float* __restrict__ SCORE){
  __shared__ __align__(16) float xlds[32*256];
  __shared__ __align__(16) float wlds[32*128];
  __shared__ float nbuf[4][256];
  __shared__ float ibuf[2][256];
  __shared__ float qpl[128];
  __shared__ float SCP[4][44];
  int bx = blockIdx.x;
  int og = bx & 3, stile = (bx>>2)&63, b = bx>>8;
  int s0 = stile*256;
  int t = threadIdx.x;
  int w = t>>6, lane = t&63;
  int ow0 = w*32;
  int tt = ISK ? 0 : 1;
  const float* Mn = MEAN + tt*32768 + b*16384 + s0;
  const float* Iv = INV  + tt*32768 + b*16384 + s0;
  const float* WB = wmat + (size_t)og*128*128;
  if (ISK){ if (t < 128) qpl[t] = QP[(b*8 + og*2)*64 + t]; }
  int col = lane*4;
  v4f mv = *(const v4f*)(Mn + col);
  v4f vv = *(const v4f*)(Iv + col);
  v4f acc[32];
  #pragma unroll
  for (int i=0;i<32;i++) acc[i] = (v4f){0.f,0.f,0.f,0.f};
  for (int kc=0;kc<4;kc++){
    __syncthreads();
    #pragma unroll
    for (int i=0;i<8;i++){
      int kk = i*4 + w;
      int cgl = kc*32 + kk;
      v4f xv = *(const v4f*)(src + ((size_t)(b*128+cgl))*S_SP + s0 + col);
      float gg = gam[cgl], bb = bet[cgl];
      v4f r;
      #pragma unroll
      for (int j=0;j<4;j++) r[j] = gg*(xv[j]-mv[j])*vv[j] + bb;
      *(v4f*)&xlds[kk*256 + col] = r;
    }
    {
      int oc = t>>1, ks0 = (t&1)*16;
      const float* wr = WB + (size_t)oc*128 + kc*32 + ks0;
      v4f w0 = *(const v4f*)wr, w1 = *(const v4f*)(wr+4);
      v4f w2 = *(const v4f*)(wr+8), w3 = *(const v4f*)(wr+12);
      #pragma unroll
      for (int i=0;i<4;i++){
        wlds[(ks0+i   )*128+oc]=w0[i];
        wlds[(ks0+i+4 )*128+oc]=w1[i];
        wlds[(ks0+i+8 )*128+oc]=w2[i];
        wlds[(ks0+i+12)*128+oc]=w3[i];
      }
    }
    __syncthreads();
    #pragma unroll 2
    for (int kk=0;kk<32;kk++){
      v4f xv = *(const v4f*)&xlds[kk*256 + col];
      #pragma unroll
      for (int o8=0;o8<8;o8++){
        v4f w4 = *(const v4f*)&wlds[kk*128 + ow0 + o8*4];
        acc[o8*4+0] += xv*w4[0];
        acc[o8*4+1] += xv*w4[1];
        acc[o8*4+2] += xv*w4[2];
        acc[o8*4+3] += xv*w4[3];
      }
    }
  }
  v4f ss = {0.f,0.f,0.f,0.f};
  #pragma unroll
  for (int o=0;o<32;o++) ss += acc[o]*acc[o];
  *(v4f*)&nbuf[w][col] = ss;
  __syncthreads();
  if (t < 256){
    float a0 = nbuf[0][t]+nbuf[1][t];
    float a1 = nbuf[2][t]+nbuf[3][t];
    ibuf[0][t] = 1.f/fmaxf(sqrtf(a0),1e-12f);
    ibuf[1][t] = 1.f/fmaxf(sqrtf(a1),1e-12f);
  }
  __syncthreads();
  int hl = w>>1;
  v4f iv4 = *(const v4f*)&ibuf[hl][col];
  int head = og*2 + hl, bh = b*8 + head;
  if (!ISK){
    #pragma unroll
    for (int o=0;o<32;o++) acc[o] *= iv4;
    #pragma unroll
    for (int j=0;j<4;j++){
      int s = s0 + col + j;
      unsigned short* dst = QBF + ((size_t)bh*S_SP + s)*64 + (w&1)*32;
      #pragma unroll
      for (int v=0;v<4;v++){
        uint4 pk;
        pk.x = pk2(acc[v*8+0][j], acc[v*8+1][j]);
        pk.y = pk2(acc[v*8+2][j], acc[v*8+3][j]);
        pk.z = pk2(acc[v*8+4][j], acc[v*8+5][j]);
        pk.w = pk2(acc[v*8+6][j], acc[v*8+7][j]);
        *(uint4*)(dst + v*8) = pk;
      }
    }
    float mine = 0.f;
    #pragma unroll
    for (int o=0;o<32;o++){
      float v = acc[o][0]+acc[o][1]+acc[o][2]+acc[o][3];
      v += __shfl_xor(v,1,64); v += __shfl_xor(v,2,64); v += __shfl_xor(v,4,64);
      v += __shfl_xor(v,8,64); v += __shfl_xor(v,16,64); v += __shfl_xor(v,32,64);
      if (lane == o) mine = v;
    }
    if (lane < 32) atomicAdd(QP + bh*64 + (w&1)*32 + lane, mine);
  } else {
    v4f tj = {0.f,0.f,0.f,0.f};
    #pragma unroll
    for (int o=0;o<32;o++){
      float qw = qpl[ow0+o];
      v4f av;
      #pragma unroll
      for (int j=0;j<4;j++) av[j] = fabsf(acc[o][j]);
      tj += av*qw;
    }
    tj *= iv4;
    v4f twv = tj;
    #pragma unroll
    for (int m=8;m<=32;m<<=1){
      v4f o2;
      #pragma unroll
      for (int j=0;j<4;j++) o2[j] = __shfl_xor(twv[j], m, 64);
      twv += o2;
    }
    float th = tj[0]+tj[1]+tj[2]+tj[3];
    th += __shfl_xor(th,1,64); th += __shfl_xor(th,2,64); th += __shfl_xor(th,4,64);
    float td = twv[0]+twv[1]+twv[2]+twv[3];
    td += __shfl_xor(td,1,64); td += __shfl_xor(td,2,64); td += __shfl_xor(td,4,64);
    if (lane == 0) SCP[w][0] = td;
    if ((lane&7) == 0) SCP[w][1 + (lane>>3)] = th;
    if (lane < 8){
      #pragma unroll
      for (int j=0;j<4;j++) SCP[w][9 + lane*4 + j] = twv[j];
    }
    __syncthreads();
    if (t < 82){
      int hl2 = t/41, slot = t - hl2*41;
      float v = SCP[hl2*2][slot] + SCP[hl2*2+1][slot];
      int bh2 = b*8 + og*2 + hl2;
      int off;
      if (slot == 0) off = stile>>2;
      else if (slot < 9) off = 16 + (stile&3)*8 + (slot-1);
      else off = 48 + (slot-9);
      atomicAdd(SCORE + bh2*80 + off, v);
    }
  }
}

// ---------------- K3: top-8 per axis from accumulated scores ---------------
__global__ __launch_bounds__(64) void k_topk(const float* __restrict__ SCORE,
                                             int* __restrict__ IDX){
  int bh = blockIdx.x;
  if (threadIdx.x != 0) return;
  float sc[80];
  for (int i=0;i<80;i++) sc[i] = SCORE[bh*80+i];
  for (int a=0;a<3;a++){
    int n = a ? 32 : 16;
    int off = (a==0) ? 0 : (a==1 ? 16 : 48);
    for (int it=0; it<8; it++){
      int bi = 0; float bv = -3.4e38f;
      for (int i=0;i<n;i++){ float v = sc[off+i]; if (v > bv){ bv=v; bi=i; } }
      IDX[bh*24 + a*8 + it] = bi;
      sc[off+bi] = -3.4e38f;
    }
  }
}

// ---------------- K4: recompute gathered k (l2norm, bf16) and v (bf16^T) ---
__global__ __launch_bounds__(256) void k_gather(const float* __restrict__ ctx,
    const float* __restrict__ wkv, const float* __restrict__ ctx_g,
    const float* __restrict__ ctx_b, const float* __restrict__ MEAN,
    const float* __restrict__ INV, const int* __restrict__ IDX,
    unsigned short* __restrict__ KG, unsigned short* __restrict__ VGT){
  __shared__ float wlds[64*129];
  __shared__ float xln[32*128];
  __shared__ int sidx[24];
  int bx = blockIdx.x;
  int bh = bx >> 5, jc = (bx >> 1) & 15, type = bx & 1;
  int head = bh & 7, b = bh >> 3;
  int t = threadIdx.x;
  if (t < 24) sidx[t] = IDX[bh*24 + t];
  {
    int oc = t>>2, ks = (t&3)*32;
    const float* wr = wkv + ((size_t)(type*512 + head*64 + oc))*128 + ks;
    #pragma unroll 8
    for (int i=0;i<32;i++) wlds[oc*129 + ks + i] = wr[i];
  }
  __syncthreads();
  {
    int jl = t>>3, seg = (t&7)*16;
    int jj = jc*32 + jl;
    int dsel = sidx[jj>>6], hsel = sidx[8 + ((jj>>3)&7)], wsel = sidx[16 + (jj&7)];
    int sj = dsel*1024 + hsel*32 + wsel;
    float mn = MEAN[b*S_SP + sj];
    float iv = INV[b*S_SP + sj];
    #pragma unroll
    for (int i=0;i<16;i++){
      int cc = seg + i;
      float raw = ctx[((size_t)(b*128 + cc))*S_SP + sj];
      xln[jl*128 + cc] = ctx_g[cc]*(raw - mn)*iv + ctx_b[cc];
    }
  }
  __syncthreads();
  int c = t & 63, jg = t >> 6;
  float accv[8] = {};
  #pragma unroll 4
  for (int k=0;k<128;k++){
    float wv = wlds[c*129 + k];
    #pragma unroll
    for (int m=0;m<8;m++) accv[m] += wv * xln[(jg + 4*m)*128 + k];
  }
  #pragma unroll
  for (int m=0;m<8;m++){
    int jj = jc*32 + jg + 4*m;
    float a = accv[m];
    if (type == 0){
      float sq = a*a;
      #pragma unroll
      for (int mm=32; mm; mm>>=1) sq += __shfl_xor(sq, mm, 64);
      float rn = 1.f/fmaxf(sqrtf(sq), 1e-12f);
      KG[((size_t)bh*NKV + jj)*64 + c] = f2bf(a*rn);
    } else {
      VGT[((size_t)bh*64 + c)*NKV + jj] = f2bf(a);
    }
  }
}

// ---------------- K5: attention. DMA-staged KV, P stays in registers -------
// S^T = K.Q^T (16x16x32): C-layout (q=l15, j=quad*4+r) is ALSO the B-operand
// layout of v_mfma_f32_16x16x16_bf16 (B[k=quad*4+i][n=lane&15]). So
// O^T = V^T.P with V^T as A from LDS (uint2) and P straight from registers.
// O^T C-layout gives each lane 4 consecutive c per quad -> packed uint2
// stores (no write amplification). Fixed-max softmax (|sim|<=1).
__global__ __launch_bounds__(512, 4) void k_attn(const unsigned short* __restrict__ QBF,
    const unsigned short* __restrict__ KG, const unsigned short* __restrict__ VGT,
    unsigned short* __restrict__ AOUT){
  __shared__ __align__(16) unsigned short kst0[8224]; // K chunk buf A (128j x 64c, group-offset)
  __shared__ __align__(16) unsigned short kst1[8224]; // K chunk buf B
  __shared__ __align__(16) unsigned short vst[8432];  // V chunk (64c x 128j, 528-stride groups)
  int bx = blockIdx.x;
  int bh = bx >> 5, qb = bx & 31;
  int t = threadIdx.x;
  int wv = t >> 6, lane = t & 63;
  int quad = lane >> 4, l15 = lane & 15;
  int q0 = qb*512 + wv*64;
  const unsigned short* kgb = KG + (size_t)bh*NKV*64;
  const unsigned short* vgb = VGT + (size_t)bh*64*NKV;
  const unsigned short* ksrcA = kgb + ((size_t)(wv*8 + (lane>>3))*64 + (lane&7)*8);
  const unsigned short* vsrcA = vgb + ((size_t)(wv*4 + (lane>>4))*512 + (lane&15)*8);
  int kdoffA = wv*512 + (wv&1)*32;
  unsigned short* vdstA = vst + wv*528;
  int koff = (l15>>3)*544 + (l15&7)*64 + quad*8;
  int voff = (l15>>2)*528 + (l15&3)*128 + quad*4;
  // Q fragments (B-operand of 16x16x32): n=q=l15, k=c=quad*8+i
  short8 bq[4][2];
  #pragma unroll
  for (int qt=0; qt<4; qt++){
    const unsigned short* qp_ = QBF + ((size_t)bh*S_SP + q0 + qt*16 + l15)*64 + quad*8;
    union { uint4 u; short8 s; } u0, u1;
    u0.u = *(const uint4*)(qp_);
    u1.u = *(const uint4*)(qp_ + 32);
    bq[qt][0] = u0.s; bq[qt][1] = u1.s;
  }
  v4f oacc[4][4]; // [qt][ct]: O^T tile: col=q=l15, row=c=ct*16+quad*4+r
  #pragma unroll
  for (int i=0;i<4;i++)
    #pragma unroll
    for (int j=0;j<4;j++) oacc[i][j] = (v4f){0.f,0.f,0.f,0.f};
  float lsum[4] = {0.f,0.f,0.f,0.f};
  // prologue: K chunk 0
  dma16(ksrcA, kst0 + kdoffA);
  dma16(ksrcA + 4096, kst0 + kdoffA + 4096);
  for (int ch=0; ch<4; ch++){
    unsigned short* kb = (ch&1) ? kst1 : kst0;
    bar_lgkm();                       // vst reads done across waves; K prefetch stays in flight
    dma16(vsrcA + ch*128, vdstA);
    dma16(vsrcA + ch*128 + 16384, vdstA + 4224);
    if (ch < 3){
      unsigned short* kn = (ch&1) ? kst0 : kst1;
      dma16(ksrcA + (ch+1)*8192, kn + kdoffA);
      dma16(ksrcA + (ch+1)*8192 + 4096, kn + kdoffA + 4096);
      bar_vm2();                      // drain K(ch)+V(ch), keep K(ch+1) in flight
    } else {
      bar_vm0();
    }
    #pragma unroll 2
    for (int jt=0; jt<8; jt++){
      const unsigned short* kr = kb + jt*1024 + koff;
      union { uint4 u; short8 s; } a0, a1;
      a0.u = *(const uint4*)(kr);
      a1.u = *(const uint4*)(kr + 32);
      short4_t aV[4];   // V^T A-fragment: m=c=ct*16+l15, k=j=jt*16+quad*4+i
      #pragma unroll
      for (int ct=0; ct<4; ct++){
        union { uint2 u2; short4_t s; } vvv;
        vvv.u2 = *(const uint2*)(vst + ct*2112 + voff + jt*16);
        aV[ct] = vvv.s;
      }
      #pragma unroll
      for (int qt=0; qt<4; qt++){
        v4f z = {0.f,0.f,0.f,0.f};
        z = __builtin_amdgcn_mfma_f32_16x16x32_bf16(a0.s, bq[qt][0], z, 0, 0, 0);
        z = __builtin_amdgcn_mfma_f32_16x16x32_bf16(a1.s, bq[qt][1], z, 0, 0, 0);
        v4f p;
        #pragma unroll
        for (int r=0;r<4;r++) p[r] = __expf(z[r] - 1.0f);
        lsum[qt] += (p[0]+p[1]) + (p[2]+p[3]);
        union { unsigned u[2]; short4_t s; } pa; // P as B-operand: k=j=quad*4+i, n=q=l15
        pa.u[0] = pk2(p[0], p[1]);
        pa.u[1] = pk2(p[2], p[3]);
        #pragma unroll
        for (int ct=0; ct<4; ct++)
          oacc[qt][ct] = mfma16(aV[ct], pa.s, oacc[qt][ct]);
      }
    }
  }
  #pragma unroll
  for (int qt=0; qt<4; qt++){
    float l = lsum[qt];
    l += __shfl_xor(l, 16, 64);
    l += __shfl_xor(l, 32, 64);
    float rl = 1.f / l;   // valid per-lane: this lane's q = qt*16 + l15
    #pragma unroll
    for (int ct=0; ct<4; ct++){
      v4f o = oacc[qt][ct];
      uint2 wv_;
      wv_.x = pk2(o[0]*rl, o[1]*rl);
      wv_.y = pk2(o[2]*rl, o[3]*rl);
      *(uint2*)(AOUT + ((size_t)bh*S_SP + q0 + qt*16 + l15)*64 + ct*16 + quad*4) = wv_;
    }
  }
}

// ---------------- K6: out-projection, W/A straight from L2 + LN + residual --
__global__ __launch_bounds__(256) void k_out(const unsigned short* __restrict__ AOUT,
    const unsigned short* __restrict__ WBF, const float* __restrict__ out_g,
    const float* __restrict__ out_b, const float* __restrict__ gamma,
    const float* __restrict__ qsrc, float* __restrict__ OUT){
  __shared__ float lnp[4][2][64];
  __shared__ float mbuf[64], sbuf[64], ogl[128], obl[128];
  int bx = blockIdx.x; int b = bx>>8; int stile = bx&255; int s0 = stile*64;
  int t = threadIdx.x; int w = t>>6; int lane = t&63;
  int q = lane>>4; int l15 = lane&15;
  if (t < 128){ ogl[t] = out_g[t]; obl[t] = out_b[t]; }
  v4f acc[2][4];
  #pragma unroll
  for (int i=0;i<2;i++)
    #pragma unroll
    for (int j=0;j<4;j++) acc[i][j] = (v4f){0.f,0.f,0.f,0.f};
  #pragma unroll 4
  for (int kt=0; kt<16; kt++){
    union { uint4 u; short8 s; } af0, af1;
    const unsigned short* wr = WBF + (size_t)(w*32 + l15)*512 + kt*32 + q*8;
    af0.u = *(const uint4*)(wr);
    af1.u = *(const uint4*)(wr + 16*512);
    int head = kt>>1; int cc0 = (kt&1)*32 + q*8;
    const unsigned short* bp = AOUT + ((size_t)((b*8+head)*S_SP + s0 + l15))*64 + cc0;
    #pragma unroll
    for (int nt=0;nt<4;nt++){
      union { uint4 u; short8 s; } ub;
      ub.u = *(const uint4*)(bp + (size_t)nt*16*64);
      acc[0][nt] = __builtin_amdgcn_mfma_f32_16x16x32_bf16(af0.s, ub.s, acc[0][nt], 0, 0, 0);
      acc[1][nt] = __builtin_amdgcn_mfma_f32_16x16x32_bf16(af1.s, ub.s, acc[1][nt], 0, 0, 0);
    }
  }
  #pragma unroll
  for (int nt=0;nt<4;nt++){
    float p1 = 0.f, p2 = 0.f;
    #pragma unroll
    for (int mt=0;mt<2;mt++)
      #pragma unroll
      for (int r=0;r<4;r++){ float v = acc[mt][nt][r]; p1 += v; p2 += v*v; }
    p1 += __shfl_xor(p1,16,64); p1 += __shfl_xor(p1,32,64);
    p2 += __shfl_xor(p2,16,64); p2 += __shfl_xor(p2,32,64);
    if (q == 0){ lnp[w][0][nt*16+l15] = p1; lnp[w][1][nt*16+l15] = p2; }
  }
  __syncthreads();
  if (t < 64){
    float m = (lnp[0][0][t]+lnp[1][0][t]+lnp[2][0][t]+lnp[3][0][t]) * 0.0078125f;
    float qq = (lnp[0][1][t]+lnp[1][1][t]+lnp[2][1][t]+lnp[3][1][t]) * 0.0078125f;
    float var = fmaxf(qq - m*m, 0.f);
    mbuf[t] = m;
    sbuf[t] = 1.f/(sqrtf(var) + 1e-6f);
  }
  __syncthreads();
  float gs = gamma[0];
  #pragma unroll
  for (int nt=0;nt<4;nt++){
    int sl = nt*16 + l15;
    float mm = mbuf[sl], ssc = sbuf[sl];
    #pragma unroll
    for (int mt=0;mt<2;mt++){
      #pragma unroll
      for (int r=0;r<4;r++){
        int c = w*32 + mt*16 + q*4 + r;
        size_t adr = ((size_t)(b*128+c))*S_SP + s0 + sl;
        float yn = (acc[mt][nt][r]-mm)*ssc;
        OUT[adr] = gs*(ogl[c]*yn + obl[c]) + qsrc[adr];
      }
    }
  }
}

extern "C" void kernel_launch(void* const* d_in, const int* in_sizes, int n_in,
                              void* d_out, int out_size, void* d_ws, size_t ws_size,
                              hipStream_t stream){
  const float* qsrc  = (const float*)d_in[0];
  const float* ctx   = (const float*)d_in[1];
  const float* wq    = (const float*)d_in[2];
  const float* wkv   = (const float*)d_in[3];
  const float* wout  = (const float*)d_in[4];
  const float* ctx_g = (const float*)d_in[5];
  const float* ctx_b = (const float*)d_in[6];
  const float* qs_g  = (const float*)d_in[7];
  const float* qs_b  = (const float*)d_in[8];
  const float* out_g = (const float*)d_in[9];
  const float* out_b = (const float*)d_in[10];
  const float* gamma = (const float*)d_in[11];
  float* OUT = (float*)d_out;
  char* ws = (char*)d_ws;
  float* QP    = (float*)(ws);
  float* SCORE = (float*)(ws + 4096);
  float* MEAN  = (float*)(ws + 16384);
  float* INV   = (float*)(ws + 278528);
  int*   IDX   = (int*)(ws + 540672);
  unsigned short* QBF  = (unsigned short*)(ws + 544768);
  unsigned short* KG   = (unsigned short*)(ws + 34099200);
  unsigned short* VGT  = (unsigned short*)(ws + 35147776);
  unsigned short* AOUT = (unsigned short*)(ws + 36196352);
  unsigned short* WBF  = (unsigned short*)(ws + 69750784);

  hipMemsetAsync(ws, 0, 9216, stream); // QP + SCORE
  k_wcvt<<<32, 256, 0, stream>>>(wout, WBF);
  k_stats<<<1024, 256, 0, stream>>>(ctx, qsrc, MEAN, INV);
  k_projT<0><<<512, 256, 0, stream>>>(qsrc, wq, qs_g, qs_b, MEAN, INV, QBF, QP, SCORE);
  k_projT<1><<<512, 256, 0, stream>>>(ctx, wkv, ctx_g, ctx_b, MEAN, INV, QBF, QP, SCORE);
  k_topk<<<16, 64, 0, stream>>>(SCORE, IDX);
  k_gather<<<512, 256, 0, stream>>>(ctx, wkv, ctx_g, ctx_b, MEAN, INV, IDX, KG, VGT);
  k_attn<<<512, 512, 0, stream>>>(QBF, KG, VGT, AOUT);
  k_out<<<512, 256, 0, stream>>>(AOUT, WBF, out_g, out_b, gamma, qsrc, OUT);
}

// Round 6
// 380.619 us; speedup vs baseline: 1.1841x; 1.1155x over previous
//
#include <hip/hip_runtime.h>
#include <hip/hip_bf16.h>

#define S_SP 16384
#define NKV 512

typedef short short8 __attribute__((ext_vector_type(8)));
typedef short short4_t __attribute__((ext_vector_type(4)));
typedef float v4f   __attribute__((ext_vector_type(4)));

__device__ __forceinline__ unsigned short f2bf(float x){
  union { float f; unsigned u; } v; v.f = x;
  unsigned r = v.u + 0x7FFFu + ((v.u >> 16) & 1u);
  return (unsigned short)(r >> 16);
}
__device__ __forceinline__ float bf2f(unsigned short h){
  union { unsigned u; float f; } v; v.u = ((unsigned)h) << 16; return v.f;
}

#if defined(__has_builtin)
#if __has_builtin(__builtin_amdgcn_cvt_pk_bf16_f32)
#define HAVE_PKBF 1
#endif
#endif

__device__ __forceinline__ unsigned pk2(float a, float b){
#ifdef HAVE_PKBF
  typedef __bf16 bf16x2 __attribute__((ext_vector_type(2)));
  union { bf16x2 v; unsigned u; } r;
  r.v = __builtin_amdgcn_cvt_pk_bf16_f32(a, b);
  return r.u;
#else
  return (unsigned)f2bf(a) | ((unsigned)f2bf(b) << 16);
#endif
}

__device__ __forceinline__ v4f mfma16(short4_t a, short4_t b, v4f c){
#if __has_builtin(__builtin_amdgcn_mfma_f32_16x16x16bf16_1k)
  return __builtin_amdgcn_mfma_f32_16x16x16bf16_1k(a, b, c, 0, 0, 0);
#else
  asm volatile("s_nop 1\n\tv_mfma_f32_16x16x16_bf16 %0, %1, %2, %0"
               : "+v"(c) : "v"(a), "v"(b));
  return c;
#endif
}

// ---------------- K0: one-time w_out fp32 -> bf16 --------------------------
__global__ __launch_bounds__(256) void k_wcvt(const float* __restrict__ w,
                                              unsigned short* __restrict__ o){
  int i = (blockIdx.x*256 + threadIdx.x)*8;
  v4f a = *(const v4f*)(w+i), b = *(const v4f*)(w+i+4);
  uint4 u;
  u.x = pk2(a[0],a[1]); u.y = pk2(a[2],a[3]);
  u.z = pk2(b[0],b[1]); u.w = pk2(b[2],b[3]);
  *(uint4*)(o+i) = u;
}

// ---------------- K1: channel-LN stats (mean, 1/(std+eps)) for ctx & qs ----
__global__ __launch_bounds__(256) void k_stats(const float* __restrict__ ctx,
                                               const float* __restrict__ qs,
                                               float* __restrict__ MEAN,
                                               float* __restrict__ INV){
  __shared__ float r1[4][64];
  __shared__ float r2[4][64];
  int bx = blockIdx.x;
  int tt = bx >> 9; int b = (bx >> 8) & 1; int sc = bx & 255;
  int t = threadIdx.x;
  int sv = t & 63, cg = t >> 6;
  int s = sc*64 + sv;
  const float* src = (tt ? qs : ctx) + ((size_t)b*128 + cg*32)*S_SP + s;
  float sum = 0.f, ss = 0.f;
  #pragma unroll 8
  for (int c = 0; c < 32; c++){
    float v = src[(size_t)c*S_SP];
    sum += v; ss += v*v;
  }
  r1[cg][sv] = sum; r2[cg][sv] = ss;
  __syncthreads();
  if (t < 64){
    float sm = r1[0][t]+r1[1][t]+r1[2][t]+r1[3][t];
    float sq = r2[0][t]+r2[1][t]+r2[2][t]+r2[3][t];
    float mean = sm * 0.0078125f;
    float var  = fmaxf(sq * 0.0078125f - mean*mean, 0.f);
    int o = tt*2*S_SP + b*S_SP + sc*64 + t;
    MEAN[o] = mean;
    INV[o]  = 1.f/(sqrtf(var) + 1e-6f);
  }
}

// ---------------- K2: fused LN + projection, W-broadcast register GEMM -----
template<int ISK>
__global__ __launch_bounds__(256) void k_projT(
    const float* __restrict__ src, const float* __restrict__ wmat,
    const float* __restrict__ gam, const float* __restrict__ bet,
    const float* __restrict__ MEAN, const float* __restrict__ INV,
    unsigned short* __restrict__ QBF, float* __restrict__ QP,
    float* __restrict__ SCORE){
  __shared__ __align__(16) float xlds[32*256];
  __shared__ __align__(16) float wlds[32*128];
  __shared__ float nbuf[4][256];
  __shared__ float ibuf[2][256];
  __shared__ float qpl[128];
  __shared__ float SCP[4][44];
  int bx = blockIdx.x;
  int og = bx & 3, stile = (bx>>2)&63, b = bx>>8;
  int s0 = stile*256;
  int t = threadIdx.x;
  int w = t>>6, lane = t&63;
  int ow0 = w*32;
  int tt = ISK ? 0 : 1;
  const float* Mn = MEAN + tt*32768 + b*16384 + s0;
  const float* Iv = INV  + tt*32768 + b*16384 + s0;
  const float* WB = wmat + (size_t)og*128*128;
  if (ISK){ if (t < 128) qpl[t] = QP[(b*8 + og*2)*64 + t]; }
  int col = lane*4;
  v4f mv = *(const v4f*)(Mn + col);
  v4f vv = *(const v4f*)(Iv + col);
  v4f acc[32];
  #pragma unroll
  for (int i=0;i<32;i++) acc[i] = (v4f){0.f,0.f,0.f,0.f};
  for (int kc=0;kc<4;kc++){
    __syncthreads();
    #pragma unroll
    for (int i=0;i<8;i++){
      int kk = i*4 + w;
      int cgl = kc*32 + kk;
      v4f xv = *(const v4f*)(src + ((size_t)(b*128+cgl))*S_SP + s0 + col);
      float gg = gam[cgl], bb = bet[cgl];
      v4f r;
      #pragma unroll
      for (int j=0;j<4;j++) r[j] = gg*(xv[j]-mv[j])*vv[j] + bb;
      *(v4f*)&xlds[kk*256 + col] = r;
    }
    {
      int oc = t>>1, ks0 = (t&1)*16;
      const float* wr = WB + (size_t)oc*128 + kc*32 + ks0;
      v4f w0 = *(const v4f*)wr, w1 = *(const v4f*)(wr+4);
      v4f w2 = *(const v4f*)(wr+8), w3 = *(const v4f*)(wr+12);
      #pragma unroll
      for (int i=0;i<4;i++){
        wlds[(ks0+i   )*128+oc]=w0[i];
        wlds[(ks0+i+4 )*128+oc]=w1[i];
        wlds[(ks0+i+8 )*128+oc]=w2[i];
        wlds[(ks0+i+12)*128+oc]=w3[i];
      }
    }
    __syncthreads();
    #pragma unroll 2
    for (int kk=0;kk<32;kk++){
      v4f xv = *(const v4f*)&xlds[kk*256 + col];
      #pragma unroll
      for (int o8=0;o8<8;o8++){
        v4f w4 = *(const v4f*)&wlds[kk*128 + ow0 + o8*4];
        acc[o8*4+0] += xv*w4[0];
        acc[o8*4+1] += xv*w4[1];
        acc[o8*4+2] += xv*w4[2];
        acc[o8*4+3] += xv*w4[3];
      }
    }
  }
  v4f ss = {0.f,0.f,0.f,0.f};
  #pragma unroll
  for (int o=0;o<32;o++) ss += acc[o]*acc[o];
  *(v4f*)&nbuf[w][col] = ss;
  __syncthreads();
  if (t < 256){
    float a0 = nbuf[0][t]+nbuf[1][t];
    float a1 = nbuf[2][t]+nbuf[3][t];
    ibuf[0][t] = 1.f/fmaxf(sqrtf(a0),1e-12f);
    ibuf[1][t] = 1.f/fmaxf(sqrtf(a1),1e-12f);
  }
  __syncthreads();
  int hl = w>>1;
  v4f iv4 = *(const v4f*)&ibuf[hl][col];
  int head = og*2 + hl, bh = b*8 + head;
  if (!ISK){
    #pragma unroll
    for (int o=0;o<32;o++) acc[o] *= iv4;
    #pragma unroll
    for (int j=0;j<4;j++){
      int s = s0 + col + j;
      unsigned short* dst = QBF + ((size_t)bh*S_SP + s)*64 + (w&1)*32;
      #pragma unroll
      for (int v=0;v<4;v++){
        uint4 pk;
        pk.x = pk2(acc[v*8+0][j], acc[v*8+1][j]);
        pk.y = pk2(acc[v*8+2][j], acc[v*8+3][j]);
        pk.z = pk2(acc[v*8+4][j], acc[v*8+5][j]);
        pk.w = pk2(acc[v*8+6][j], acc[v*8+7][j]);
        *(uint4*)(dst + v*8) = pk;
      }
    }
    float mine = 0.f;
    #pragma unroll
    for (int o=0;o<32;o++){
      float v = acc[o][0]+acc[o][1]+acc[o][2]+acc[o][3];
      v += __shfl_xor(v,1,64); v += __shfl_xor(v,2,64); v += __shfl_xor(v,4,64);
      v += __shfl_xor(v,8,64); v += __shfl_xor(v,16,64); v += __shfl_xor(v,32,64);
      if (lane == o) mine = v;
    }
    if (lane < 32) atomicAdd(QP + bh*64 + (w&1)*32 + lane, mine);
  } else {
    v4f tj = {0.f,0.f,0.f,0.f};
    #pragma unroll
    for (int o=0;o<32;o++){
      float qw = qpl[ow0+o];
      v4f av;
      #pragma unroll
      for (int j=0;j<4;j++) av[j] = fabsf(acc[o][j]);
      tj += av*qw;
    }
    tj *= iv4;
    v4f twv = tj;
    #pragma unroll
    for (int m=8;m<=32;m<<=1){
      v4f o2;
      #pragma unroll
      for (int j=0;j<4;j++) o2[j] = __shfl_xor(twv[j], m, 64);
      twv += o2;
    }
    float th = tj[0]+tj[1]+tj[2]+tj[3];
    th += __shfl_xor(th,1,64); th += __shfl_xor(th,2,64); th += __shfl_xor(th,4,64);
    float td = twv[0]+twv[1]+twv[2]+twv[3];
    td += __shfl_xor(td,1,64); td += __shfl_xor(td,2,64); td += __shfl_xor(td,4,64);
    if (lane == 0) SCP[w][0] = td;
    if ((lane&7) == 0) SCP[w][1 + (lane>>3)] = th;
    if (lane < 8){
      #pragma unroll
      for (int j=0;j<4;j++) SCP[w][9 + lane*4 + j] = twv[j];
    }
    __syncthreads();
    if (t < 82){
      int hl2 = t/41, slot = t - hl2*41;
      float v = SCP[hl2*2][slot] + SCP[hl2*2+1][slot];
      int bh2 = b*8 + og*2 + hl2;
      int off;
      if (slot == 0) off = stile>>2;
      else if (slot < 9) off = 16 + (stile&3)*8 + (slot-1);
      else off = 48 + (slot-9);
      atomicAdd(SCORE + bh2*80 + off, v);
    }
  }
}

// ---------------- K3: top-8 per axis from accumulated scores ---------------
__global__ __launch_bounds__(64) void k_topk(const float* __restrict__ SCORE,
                                             int* __restrict__ IDX){
  int bh = blockIdx.x;
  if (threadIdx.x != 0) return;
  float sc[80];
  for (int i=0;i<80;i++) sc[i] = SCORE[bh*80+i];
  for (int a=0;a<3;a++){
    int n = a ? 32 : 16;
    int off = (a==0) ? 0 : (a==1 ? 16 : 48);
    for (int it=0; it<8; it++){
      int bi = 0; float bv = -3.4e38f;
      for (int i=0;i<n;i++){ float v = sc[off+i]; if (v > bv){ bv=v; bi=i; } }
      IDX[bh*24 + a*8 + it] = bi;
      sc[off+bi] = -3.4e38f;
    }
  }
}

// ---------------- K4: recompute gathered k (l2norm, bf16) and v (bf16^T) ---
__global__ __launch_bounds__(256) void k_gather(const float* __restrict__ ctx,
    const float* __restrict__ wkv, const float* __restrict__ ctx_g,
    const float* __restrict__ ctx_b, const float* __restrict__ MEAN,
    const float* __restrict__ INV, const int* __restrict__ IDX,
    unsigned short* __restrict__ KG, unsigned short* __restrict__ VGT){
  __shared__ float wlds[64*129];
  __shared__ float xln[32*128];
  __shared__ int sidx[24];
  int bx = blockIdx.x;
  int bh = bx >> 5, jc = (bx >> 1) & 15, type = bx & 1;
  int head = bh & 7, b = bh >> 3;
  int t = threadIdx.x;
  if (t < 24) sidx[t] = IDX[bh*24 + t];
  {
    int oc = t>>2, ks = (t&3)*32;
    const float* wr = wkv + ((size_t)(type*512 + head*64 + oc))*128 + ks;
    #pragma unroll 8
    for (int i=0;i<32;i++) wlds[oc*129 + ks + i] = wr[i];
  }
  __syncthreads();
  {
    int jl = t>>3, seg = (t&7)*16;
    int jj = jc*32 + jl;
    int dsel = sidx[jj>>6], hsel = sidx[8 + ((jj>>3)&7)], wsel = sidx[16 + (jj&7)];
    int sj = dsel*1024 + hsel*32 + wsel;
    float mn = MEAN[b*S_SP + sj];
    float iv = INV[b*S_SP + sj];
    #pragma unroll
    for (int i=0;i<16;i++){
      int cc = seg + i;
      float raw = ctx[((size_t)(b*128 + cc))*S_SP + sj];
      xln[jl*128 + cc] = ctx_g[cc]*(raw - mn)*iv + ctx_b[cc];
    }
  }
  __syncthreads();
  int c = t & 63, jg = t >> 6;
  float accv[8] = {};
  #pragma unroll 4
  for (int k=0;k<128;k++){
    float wv = wlds[c*129 + k];
    #pragma unroll
    for (int m=0;m<8;m++) accv[m] += wv * xln[(jg + 4*m)*128 + k];
  }
  #pragma unroll
  for (int m=0;m<8;m++){
    int jj = jc*32 + jg + 4*m;
    float a = accv[m];
    if (type == 0){
      float sq = a*a;
      #pragma unroll
      for (int mm=32; mm; mm>>=1) sq += __shfl_xor(sq, mm, 64);
      float rn = 1.f/fmaxf(sqrtf(sq), 1e-12f);
      KG[((size_t)bh*NKV + jj)*64 + c] = f2bf(a*rn);
    } else {
      VGT[((size_t)bh*64 + c)*NKV + jj] = f2bf(a);
    }
  }
}

// ---------------- K5: attention. ds_write staging (in-cache), P in regs ----
// S^T = K.Q^T (16x16x32): C-layout (q=l15, j=quad*4+r) is the B-operand
// layout of v_mfma_f32_16x16x16_bf16 => O^T = V^T.P with P straight from
// registers (zero P LDS traffic). Fixed-max softmax (|sim|<=1). Staging via
// plain global loads + ds_write_b128 — measured in-cache in round 3 vs
// global_load_lds which produced ~10x HBM traffic (rounds 4-5).
__global__ __launch_bounds__(512, 4) void k_attn(const unsigned short* __restrict__ QBF,
    const unsigned short* __restrict__ KG, const unsigned short* __restrict__ VGT,
    unsigned short* __restrict__ AOUT){
  __shared__ __align__(16) unsigned short kst[128*72]; // K chunk [j][c], stride 72
  __shared__ __align__(16) unsigned short vst[64*136]; // V chunk [c][j], stride 136
  int bx = blockIdx.x;
  int bh = bx >> 5, qb = bx & 31;
  int t = threadIdx.x;
  int wv = t >> 6, lane = t & 63;
  int quad = lane >> 4, l15 = lane & 15;
  int q0 = qb*512 + wv*64;
  const unsigned short* kgb = KG + (size_t)bh*NKV*64;
  const unsigned short* vgb = VGT + (size_t)bh*64*NKV;
  // Q fragments (B-operand of 16x16x32): n=q=l15, k=c=quad*8+i
  short8 bq[4][2];
  #pragma unroll
  for (int qt=0; qt<4; qt++){
    const unsigned short* qp_ = QBF + ((size_t)bh*S_SP + q0 + qt*16 + l15)*64 + quad*8;
    union { uint4 u; short8 s; } u0, u1;
    u0.u = *(const uint4*)(qp_);
    u1.u = *(const uint4*)(qp_ + 32);
    bq[qt][0] = u0.s; bq[qt][1] = u1.s;
  }
  v4f oacc[4][4]; // [qt][ct]: O^T tile: col=q=l15, row=c=ct*16+quad*4+r
  #pragma unroll
  for (int i=0;i<4;i++)
    #pragma unroll
    for (int j=0;j<4;j++) oacc[i][j] = (v4f){0.f,0.f,0.f,0.f};
  float lsum[4] = {0.f,0.f,0.f,0.f};
  for (int ch=0; ch<4; ch++){
    __syncthreads();
    { // stage K chunk [128 j][64 c]
      int j = t>>2, seg = (t&3)*16;
      const unsigned short* sp = kgb + (size_t)(ch*128 + j)*64 + seg;
      unsigned short* dp = kst + j*72 + seg;
      *(uint4*)(dp)     = *(const uint4*)(sp);
      *(uint4*)(dp + 8) = *(const uint4*)(sp + 8);
    }
    { // stage V chunk [64 c][128 j]
      int c = t>>3, jseg = (t&7)*16;
      const unsigned short* sp = vgb + (size_t)c*NKV + ch*128 + jseg;
      unsigned short* dp = vst + c*136 + jseg;
      *(uint4*)(dp)     = *(const uint4*)(sp);
      *(uint4*)(dp + 8) = *(const uint4*)(sp + 8);
    }
    __syncthreads();
    #pragma unroll 2
    for (int jt=0; jt<8; jt++){
      const unsigned short* kr = kst + (jt*16 + l15)*72 + quad*8;
      union { uint4 u; short8 s; } a0, a1;
      a0.u = *(const uint4*)(kr);
      a1.u = *(const uint4*)(kr + 32);
      short4_t aV[4];   // V^T A-fragment: m=c=ct*16+l15, k=j=jt*16+quad*4+i
      #pragma unroll
      for (int ct=0; ct<4; ct++){
        union { uint2 u2; short4_t s; } vvv;
        vvv.u2 = *(const uint2*)(vst + (ct*16 + l15)*136 + jt*16 + quad*4);
        aV[ct] = vvv.s;
      }
      #pragma unroll
      for (int qt=0; qt<4; qt++){
        v4f z = {0.f,0.f,0.f,0.f};
        z = __builtin_amdgcn_mfma_f32_16x16x32_bf16(a0.s, bq[qt][0], z, 0, 0, 0);
        z = __builtin_amdgcn_mfma_f32_16x16x32_bf16(a1.s, bq[qt][1], z, 0, 0, 0);
        v4f p;
        #pragma unroll
        for (int r=0;r<4;r++) p[r] = __expf(z[r] - 1.0f);
        lsum[qt] += (p[0]+p[1]) + (p[2]+p[3]);
        union { unsigned u[2]; short4_t s; } pa; // P as B-operand: k=j=quad*4+i, n=q=l15
        pa.u[0] = pk2(p[0], p[1]);
        pa.u[1] = pk2(p[2], p[3]);
        #pragma unroll
        for (int ct=0; ct<4; ct++)
          oacc[qt][ct] = mfma16(aV[ct], pa.s, oacc[qt][ct]);
      }
    }
  }
  #pragma unroll
  for (int qt=0; qt<4; qt++){
    float l = lsum[qt];
    l += __shfl_xor(l, 16, 64);
    l += __shfl_xor(l, 32, 64);
    float rl = 1.f / l;   // valid per-lane: this lane's q = qt*16 + l15
    #pragma unroll
    for (int ct=0; ct<4; ct++){
      v4f o = oacc[qt][ct];
      uint2 wv_;
      wv_.x = pk2(o[0]*rl, o[1]*rl);
      wv_.y = pk2(o[2]*rl, o[3]*rl);
      *(uint2*)(AOUT + ((size_t)bh*S_SP + q0 + qt*16 + l15)*64 + ct*16 + quad*4) = wv_;
    }
  }
}

// ---------------- K6: out-projection, W/A straight from L2 + LN + residual --
__global__ __launch_bounds__(256) void k_out(const unsigned short* __restrict__ AOUT,
    const unsigned short* __restrict__ WBF, const float* __restrict__ out_g,
    const float* __restrict__ out_b, const float* __restrict__ gamma,
    const float* __restrict__ qsrc, float* __restrict__ OUT){
  __shared__ float lnp[4][2][64];
  __shared__ float mbuf[64], sbuf[64], ogl[128], obl[128];
  int bx = blockIdx.x; int b = bx>>8; int stile = bx&255; int s0 = stile*64;
  int t = threadIdx.x; int w = t>>6; int lane = t&63;
  int q = lane>>4; int l15 = lane&15;
  if (t < 128){ ogl[t] = out_g[t]; obl[t] = out_b[t]; }
  v4f acc[2][4];
  #pragma unroll
  for (int i=0;i<2;i++)
    #pragma unroll
    for (int j=0;j<4;j++) acc[i][j] = (v4f){0.f,0.f,0.f,0.f};
  #pragma unroll 4
  for (int kt=0; kt<16; kt++){
    union { uint4 u; short8 s; } af0, af1;
    const unsigned short* wr = WBF + (size_t)(w*32 + l15)*512 + kt*32 + q*8;
    af0.u = *(const uint4*)(wr);
    af1.u = *(const uint4*)(wr + 16*512);
    int head = kt>>1; int cc0 = (kt&1)*32 + q*8;
    const unsigned short* bp = AOUT + ((size_t)((b*8+head)*S_SP + s0 + l15))*64 + cc0;
    #pragma unroll
    for (int nt=0;nt<4;nt++){
      union { uint4 u; short8 s; } ub;
      ub.u = *(const uint4*)(bp + (size_t)nt*16*64);
      acc[0][nt] = __builtin_amdgcn_mfma_f32_16x16x32_bf16(af0.s, ub.s, acc[0][nt], 0, 0, 0);
      acc[1][nt] = __builtin_amdgcn_mfma_f32_16x16x32_bf16(af1.s, ub.s, acc[1][nt], 0, 0, 0);
    }
  }
  #pragma unroll
  for (int nt=0;nt<4;nt++){
    float p1 = 0.f, p2 = 0.f;
    #pragma unroll
    for (int mt=0;mt<2;mt++)
      #pragma unroll
      for (int r=0;r<4;r++){ float v = acc[mt][nt][r]; p1 += v; p2 += v*v; }
    p1 += __shfl_xor(p1,16,64); p1 += __shfl_xor(p1,32,64);
    p2 += __shfl_xor(p2,16,64); p2 += __shfl_xor(p2,32,64);
    if (q == 0){ lnp[w][0][nt*16+l15] = p1; lnp[w][1][nt*16+l15] = p2; }
  }
  __syncthreads();
  if (t < 64){
    float m = (lnp[0][0][t]+lnp[1][0][t]+lnp[2][0][t]+lnp[3][0][t]) * 0.0078125f;
    float qq = (lnp[0][1][t]+lnp[1][1][t]+lnp[2][1][t]+lnp[3][1][t]) * 0.0078125f;
    float var = fmaxf(qq - m*m, 0.f);
    mbuf[t] = m;
    sbuf[t] = 1.f/(sqrtf(var) + 1e-6f);
  }
  __syncthreads();
  float gs = gamma[0];
  #pragma unroll
  for (int nt=0;nt<4;nt++){
    int sl = nt*16 + l15;
    float mm = mbuf[sl], ssc = sbuf[sl];
    #pragma unroll
    for (int mt=0;mt<2;mt++){
      #pragma unroll
      for (int r=0;r<4;r++){
        int c = w*32 + mt*16 + q*4 + r;
        size_t adr = ((size_t)(b*128+c))*S_SP + s0 + sl;
        float yn = (acc[mt][nt][r]-mm)*ssc;
        OUT[adr] = gs*(ogl[c]*yn + obl[c]) + qsrc[adr];
      }
    }
  }
}

extern "C" void kernel_launch(void* const* d_in, const int* in_sizes, int n_in,
                              void* d_out, int out_size, void* d_ws, size_t ws_size,
                              hipStream_t stream){
  const float* qsrc  = (const float*)d_in[0];
  const float* ctx   = (const float*)d_in[1];
  const float* wq    = (const float*)d_in[2];
  const float* wkv   = (const float*)d_in[3];
  const float* wout  = (const float*)d_in[4];
  const float* ctx_g = (const float*)d_in[5];
  const float* ctx_b = (const float*)d_in[6];
  const float* qs_g  = (const float*)d_in[7];
  const float* qs_b  = (const float*)d_in[8];
  const float* out_g = (const float*)d_in[9];
  const float* out_b = (const float*)d_in[10];
  const float* gamma = (const float*)d_in[11];
  float* OUT = (float*)d_out;
  char* ws = (char*)d_ws;
  float* QP    = (float*)(ws);
  float* SCORE = (float*)(ws + 4096);
  float* MEAN  = (float*)(ws + 16384);
  float* INV   = (float*)(ws + 278528);
  int*   IDX   = (int*)(ws + 540672);
  unsigned short* QBF  = (unsigned short*)(ws + 544768);
  unsigned short* KG   = (unsigned short*)(ws + 34099200);
  unsigned short* VGT  = (unsigned short*)(ws + 35147776);
  unsigned short* AOUT = (unsigned short*)(ws + 36196352);
  unsigned short* WBF  = (unsigned short*)(ws + 69750784);

  hipMemsetAsync(ws, 0, 9216, stream); // QP + SCORE
  k_wcvt<<<32, 256, 0, stream>>>(wout, WBF);
  k_stats<<<1024, 256, 0, stream>>>(ctx, qsrc, MEAN, INV);
  k_projT<0><<<512, 256, 0, stream>>>(qsrc, wq, qs_g, qs_b, MEAN, INV, QBF, QP, SCORE);
  k_projT<1><<<512, 256, 0, stream>>>(ctx, wkv, ctx_g, ctx_b, MEAN, INV, QBF, QP, SCORE);
  k_topk<<<16, 64, 0, stream>>>(SCORE, IDX);
  k_gather<<<512, 256, 0, stream>>>(ctx, wkv, ctx_g, ctx_b, MEAN, INV, IDX, KG, VGT);
  k_attn<<<512, 512, 0, stream>>>(QBF, KG, VGT, AOUT);
  k_out<<<512, 256, 0, stream>>>(AOUT, WBF, out_g, out_b, gamma, qsrc, OUT);
}